// Round 1
// baseline (82.903 us; speedup 1.0000x reference)
//
#include <hip/hip_runtime.h>
#include <stdint.h>
#include <stddef.h>

// BlockLinear: out[b, g*512+n] = sum_m x[b, g*512+m] * blocks[g, m, n]
// G=8, M=N=512, TOKENS=8192. fp32 in/out; compute in bf16 MFMA.

typedef __attribute__((ext_vector_type(8))) short sv8;   // 8 x bf16 fragment
typedef __attribute__((ext_vector_type(4))) float fv4;   // 4 x f32 accum

__device__ __forceinline__ uint32_t f2bf(float f) {
    union { float f; uint32_t u; } v; v.f = f;
    uint32_t u = v.u;
    u += 0x7FFFu + ((u >> 16) & 1u);   // RNE
    return u >> 16;
}
__device__ __forceinline__ uint32_t pk2(float a, float b) {
    return f2bf(a) | (f2bf(b) << 16);
}

// blocksT[g][n][k] (bf16) = blocks[g][k][n] (f32)
__global__ void bl_transpose(const float* __restrict__ blocks,
                             unsigned short* __restrict__ bT) {
    __shared__ float tile[64][65];
    const int g  = blockIdx.z;
    const int k0 = blockIdx.y * 64;
    const int n0 = blockIdx.x * 64;
    const float* src = blocks + (size_t)g * 512 * 512;
    unsigned short* dst = bT + (size_t)g * 512 * 512;
    const int lane = threadIdx.x & 63;
    const int r0   = threadIdx.x >> 6;   // 0..3
    for (int r = r0; r < 64; r += 4)
        tile[r][lane] = src[(size_t)(k0 + r) * 512 + n0 + lane];
    __syncthreads();
    for (int r = r0; r < 64; r += 4)
        dst[(size_t)(n0 + r) * 512 + k0 + lane] = (unsigned short)f2bf(tile[lane][r]);
}

// Main GEMM: BM=128, BN=256, BK=64, 512 threads (8 waves, 2x4 wave grid,
// 64x64 per wave = 4x4 fragments of 16x16x32 bf16 MFMA).
__global__ __launch_bounds__(512, 2) void bl_gemm(
    const float* __restrict__ x,            // [8192][4096]
    const unsigned short* __restrict__ bT,  // [8][512 n][512 k] bf16
    float* __restrict__ out)                // [8192][4096]
{
    __shared__ __align__(16) unsigned short As[128 * 64];  // [row m][k], XOR-swizzled 16B slots
    __shared__ __align__(16) unsigned short Bs[256 * 64];  // [row n][k], XOR-swizzled 16B slots

    const int bid = blockIdx.x;
    const int g   = bid & 7;          // group == XCD (round-robin dispatch)
    const int rem = bid >> 3;
    const int nt  = rem & 1;
    const int mt  = rem >> 1;         // 0..63

    const int tid  = threadIdx.x;
    const int lane = tid & 63;
    const int wid  = tid >> 6;        // 0..7
    const int wm   = wid >> 2;        // 0..1
    const int wn   = wid & 3;         // 0..3

    fv4 acc[4][4];
#pragma unroll
    for (int i = 0; i < 4; ++i)
#pragma unroll
        for (int j = 0; j < 4; ++j)
            acc[i][j] = (fv4){0.f, 0.f, 0.f, 0.f};

    const float* xg = x + (size_t)(mt * 128) * 4096 + g * 512;
    const unsigned short* bg = bT + ((size_t)g * 512 + nt * 256) * 512;

    const int arow0 = tid >> 3;   // 0..63: staging row within pass
    const int ac8   = tid & 7;    // 16B chunk (8 bf16) within a 64-elem k-row

    for (int kt = 0; kt < 8; ++kt) {
        const int k0 = kt * 64;
        // ---- stage A: x[128][64] f32 -> bf16, swizzled ----
#pragma unroll
        for (int p = 0; p < 2; ++p) {
            const int row = p * 64 + arow0;
            const float* s = xg + (size_t)row * 4096 + k0 + ac8 * 8;
            const float4 v0 = *(const float4*)s;
            const float4 v1 = *(const float4*)(s + 4);
            uint4 w;
            w.x = pk2(v0.x, v0.y); w.y = pk2(v0.z, v0.w);
            w.z = pk2(v1.x, v1.y); w.w = pk2(v1.z, v1.w);
            const int slot = ac8 ^ (row & 7);
            *(uint4*)((char*)As + row * 128 + slot * 16) = w;
        }
        // ---- stage B^T: bT[256][64] bf16, swizzled ----
#pragma unroll
        for (int p = 0; p < 4; ++p) {
            const int row = p * 64 + arow0;
            const uint4 v = *(const uint4*)(bg + (size_t)row * 512 + k0 + ac8 * 8);
            const int slot = ac8 ^ (row & 7);
            *(uint4*)((char*)Bs + row * 128 + slot * 16) = v;
        }
        __syncthreads();

        const int lr = lane & 15;
        const int lg = lane >> 4;
#pragma unroll
        for (int kk = 0; kk < 2; ++kk) {
            const int kslot = kk * 4 + lg;   // 16B slot in k (8 bf16 per slot)
            sv8 a[4], b[4];
#pragma unroll
            for (int mi = 0; mi < 4; ++mi) {
                const int row = wm * 64 + mi * 16 + lr;
                a[mi] = *(const sv8*)((const char*)As + row * 128 + ((kslot ^ (row & 7)) * 16));
            }
#pragma unroll
            for (int ni = 0; ni < 4; ++ni) {
                const int row = wn * 64 + ni * 16 + lr;
                b[ni] = *(const sv8*)((const char*)Bs + row * 128 + ((kslot ^ (row & 7)) * 16));
            }
#pragma unroll
            for (int mi = 0; mi < 4; ++mi)
#pragma unroll
                for (int ni = 0; ni < 4; ++ni)
                    acc[mi][ni] = __builtin_amdgcn_mfma_f32_16x16x32_bf16(
                        a[mi], b[ni], acc[mi][ni], 0, 0, 0);
        }
        __syncthreads();
    }

    // ---- epilogue: D layout col=lane&15, row=(lane>>4)*4+q ----
    const int lr = lane & 15;
    const int lg = lane >> 4;
    float* og = out + (size_t)(mt * 128) * 4096 + g * 512 + nt * 256;
#pragma unroll
    for (int mi = 0; mi < 4; ++mi)
#pragma unroll
        for (int ni = 0; ni < 4; ++ni)
#pragma unroll
            for (int q = 0; q < 4; ++q) {
                const int row = wm * 64 + mi * 16 + lg * 4 + q;
                const int col = wn * 64 + ni * 16 + lr;
                og[(size_t)row * 4096 + col] = acc[mi][ni][q];
            }
}

// Safety net if ws is too small for the bf16 transposed blocks (4 MiB).
__global__ void bl_fallback(const float* __restrict__ x,
                            const float* __restrict__ blocks,
                            float* __restrict__ out) {
    const int o = blockIdx.x * 256 + threadIdx.x;
    const int col = o & 4095;
    const int row = o >> 12;
    const int g = col >> 9;
    const int n = col & 511;
    const float* xr = x + (size_t)row * 4096 + g * 512;
    const float* wp = blocks + (size_t)g * 512 * 512 + n;
    float s = 0.f;
    for (int m = 0; m < 512; ++m) s += xr[m] * wp[(size_t)m * 512];
    out[o] = s;
}

extern "C" void kernel_launch(void* const* d_in, const int* in_sizes, int n_in,
                              void* d_out, int out_size, void* d_ws, size_t ws_size,
                              hipStream_t stream) {
    const float* x      = (const float*)d_in[0];
    const float* blocks = (const float*)d_in[1];
    float* out          = (float*)d_out;

    const size_t need = (size_t)8 * 512 * 512 * sizeof(unsigned short); // 4 MiB
    if (ws_size >= need) {
        unsigned short* bT = (unsigned short*)d_ws;
        bl_transpose<<<dim3(8, 8, 8), 256, 0, stream>>>(blocks, bT);
        bl_gemm<<<1024, 512, 0, stream>>>(x, bT, out);
    } else {
        bl_fallback<<<(8192 * 4096) / 256, 256, 0, stream>>>(x, blocks, out);
    }
}